// Round 1
// 117.369 us; speedup vs baseline: 1.0680x; 1.0680x over previous
//
#include <hip/hip_runtime.h>

#define NB   32
#define NQ   300
#define NCLS 92
#define NM   50
#define BM   (NB * NM)   // 1600 flat targets
#define BQ   (NB * NQ)   // 9600 flat preds
#define HM   NQ          // hungarian cols (queries) = 300
#define HN   NM          // hungarian rows (targets) = 50
#define PITCH 305        // 305 % 32 = 17 (odd): row-scan & col-mode <=2-way (free)
#define BIG  1e30f
#define HUNG_BLOCKS NB
#define COST_ROWS_PER_BLOCK 16
#define COST_BLOCKS (BQ / COST_ROWS_PER_BLOCK)  // 600
#define NBLOCKS (HUNG_BLOCKS + COST_BLOCKS)     // 632

typedef float vf4 __attribute__((ext_vector_type(4)));

// single-wave fence: equivalent to __syncthreads() when one wave executes
#define FENCE() __threadfence_block()

// ---------------------------------------------------------------------------
// DPP cross-lane reductions (VALU, ~4-8 cyc/step) replacing ds_swizzle-based
// __shfl_xor chains (~30-40 cyc/step).  Uniform result via v_readlane(63)
// (LLVM atomic-optimizer reduction schedule: xor1, xor2, xor7, xor15,
//  row_bcast15, row_bcast31 -> lane 63 holds full reduction).
// ---------------------------------------------------------------------------
#define DPP_XOR1  0xB1   // quad_perm(1,0,3,2)
#define DPP_XOR2  0x4E   // quad_perm(2,3,0,1)
#define DPP_HMIRR 0x141  // row_half_mirror (xor 7 within 8)
#define DPP_MIRR  0x140  // row_mirror      (xor 15 within 16)
#define DPP_BC15  0x142  // row_bcast:15 -> next row
#define DPP_BC31  0x143  // row_bcast:31 -> rows 2,3

template <int C_>
__device__ __forceinline__ float dppk(float v) {  // invalid src lanes keep old
  return __int_as_float(__builtin_amdgcn_update_dpp(
      __float_as_int(v), __float_as_int(v), C_, 0xf, 0xf, false));
}
template <int C_>
__device__ __forceinline__ float dppz(float v) {  // invalid src lanes -> 0
  return __int_as_float(
      __builtin_amdgcn_update_dpp(0, __float_as_int(v), C_, 0xf, 0xf, true));
}

__device__ __forceinline__ float rl63(float v) {
  return __int_as_float(__builtin_amdgcn_readlane(__float_as_int(v), 63));
}
__device__ __forceinline__ int rli(int v, int l) {
  return __builtin_amdgcn_readlane(v, l);
}
__device__ __forceinline__ float rlf(float v, int l) {
  return __int_as_float(__builtin_amdgcn_readlane(__float_as_int(v), l));
}

__device__ __forceinline__ float wredu_max(float v) {  // uniform return
  v = fmaxf(v, dppk<DPP_XOR1>(v));
  v = fmaxf(v, dppk<DPP_XOR2>(v));
  v = fmaxf(v, dppk<DPP_HMIRR>(v));
  v = fmaxf(v, dppk<DPP_MIRR>(v));
  v = fmaxf(v, dppk<DPP_BC15>(v));
  v = fmaxf(v, dppk<DPP_BC31>(v));
  return rl63(v);
}
__device__ __forceinline__ float wredu_min(float v) {  // uniform return
  v = fminf(v, dppk<DPP_XOR1>(v));
  v = fminf(v, dppk<DPP_XOR2>(v));
  v = fminf(v, dppk<DPP_HMIRR>(v));
  v = fminf(v, dppk<DPP_MIRR>(v));
  v = fminf(v, dppk<DPP_BC15>(v));
  v = fminf(v, dppk<DPP_BC31>(v));
  return rl63(v);
}
__device__ __forceinline__ float wredu_sum(float v) {  // uniform return
  v += dppz<DPP_XOR1>(v);
  v += dppz<DPP_XOR2>(v);
  v += dppz<DPP_HMIRR>(v);
  v += dppz<DPP_MIRR>(v);
  v += dppz<DPP_BC15>(v);
  v += dppz<DPP_BC31>(v);
  return rl63(v);
}

// cost(pred, target): -prob + 5*L1 - 2*GIoU  — R2-identical precise arithmetic
__device__ __forceinline__ float pair_cost(float ax1, float ay1, float ax2,
                                           float ay2, float areaA,
                                           const float4& pb, const float4& t,
                                           float negprob) {
  float cb = fabsf(pb.x - t.x) + fabsf(pb.y - t.y) +
             fabsf(pb.z - t.z) + fabsf(pb.w - t.w);
  float bx1 = t.x - 0.5f * t.z, by1 = t.y - 0.5f * t.w;
  float bx2 = t.x + 0.5f * t.z, by2 = t.y + 0.5f * t.w;
  float areaB = (bx2 - bx1) * (by2 - by1);
  float iw = fmaxf(fminf(ax2, bx2) - fmaxf(ax1, bx1), 0.f);
  float ih = fmaxf(fminf(ay2, by2) - fmaxf(ay1, by1), 0.f);
  float inter = iw * ih;
  float uni = areaA + areaB - inter;
  float iou = inter / uni;
  float ew = fmaxf(fmaxf(ax2, bx2) - fminf(ax1, bx1), 0.f);
  float eh = fmaxf(fmaxf(ay2, by2) - fminf(ay1, by1), 0.f);
  float areaE = ew * eh;
  float giou = iou - (areaE - uni) / areaE;
  return (negprob + 5.f * cb) - 2.f * giou;
}

// wave-cooperative softmax over 92 classes -> prow[0..91] (precise expf, div)
__device__ __forceinline__ void wave_softmax(const float* __restrict__ lrow,
                                             float* prow, int lane) {
  float x0 = lrow[lane];  // lane < 64 < 92 always valid
  float x1 = (lane + 64 < NCLS) ? lrow[lane + 64] : -BIG;
  float mx = wredu_max(fmaxf(x0, x1));
  float e0 = expf(x0 - mx), e1 = expf(x1 - mx);
  float s = wredu_sum(e0 + e1);
  prow[lane] = e0 / s;
  if (lane + 64 < NCLS) prow[lane + 64] = e1 / s;
  FENCE();
}

__global__ __launch_bounds__(1024) void fused_kernel(
    const float* __restrict__ logits, const float* __restrict__ pboxes,
    const int* __restrict__ tlab, const float* __restrict__ tbox,
    float* __restrict__ outp) {
  __shared__ float hc[HN * PITCH];      // 61000 B (hungarian path only)
  __shared__ float probs_s[16][NCLS];   // 5888 B (cost path only)
  __shared__ int   p[HM + 1];
  __shared__ int   way[HM];
  __shared__ int   qarr[HN];

  float* C = outp + 2 * BM;
  int tid = threadIdx.x, wave = tid >> 6, lane = tid & 63;

  if (blockIdx.x >= HUNG_BLOCKS) {
    // ---------------- cost-matrix path: one pred row per wave ----------------
    int row = (blockIdx.x - HUNG_BLOCKS) * COST_ROWS_PER_BLOCK + wave;
    wave_softmax(logits + (size_t)row * NCLS, probs_s[wave], lane);

    float4 pb = reinterpret_cast<const float4*>(pboxes)[row];
    float ax1 = pb.x - 0.5f * pb.z, ay1 = pb.y - 0.5f * pb.w;
    float ax2 = pb.x + 0.5f * pb.z, ay2 = pb.y + 0.5f * pb.w;
    float areaA = (ax2 - ax1) * (ay2 - ay1);

    const float4* tbv = reinterpret_cast<const float4*>(tbox);
    const int4*   tlv = reinterpret_cast<const int4*>(tlab);
    vf4* crow = reinterpret_cast<vf4*>(C + (size_t)row * BM);
    for (int q4 = lane; q4 < BM / 4; q4 += 64) {
      int4 cls = tlv[q4];
      int clsa[4] = {cls.x, cls.y, cls.z, cls.w};
      vf4 o;
#pragma unroll
      for (int e = 0; e < 4; e++) {
        float4 t = tbv[q4 * 4 + e];
        o[e] = pair_cost(ax1, ay1, ax2, ay2, areaA, pb, t,
                         -probs_s[wave][clsa[e]]);
      }
      __builtin_nontemporal_store(o, &crow[q4]);
    }
    return;
  }

  // ---------------- hungarian path: batch b = blockIdx.x ----------------
  int b = blockIdx.x;

  // init p (all threads; covered by the barrier below)
  for (int x = tid; x <= HM; x += 1024) p[x] = -1;

  // preload this batch's 50 targets into lane registers
  float4 t_reg = make_float4(0.f, 0.f, 0.f, 0.f);
  int cls_reg = 0;
  if (lane < NM) {
    t_reg = reinterpret_cast<const float4*>(tbox)[b * NM + lane];
    cls_reg = tlab[b * NM + lane];
  }

  // stage hc[i][q] = cost(pred (b,q), target (b,i)) with all 16 waves.
  // NO LDS probs / NO FENCE here: the single needed prob per lane is gathered
  // from the in-register logit row via ds_bpermute, so consecutive q
  // iterations software-pipeline their global loads.
  const float4* pbv = reinterpret_cast<const float4*>(pboxes);
  for (int q = wave; q < NQ; q += 16) {
    const float* lrow = logits + (size_t)(b * NQ + q) * NCLS;
    float x0 = lrow[lane];
    float x1 = (lane + 64 < NCLS) ? lrow[lane + 64] : -BIG;
    float mx = wredu_max(fmaxf(x0, x1));
    float e0 = expf(x0 - mx), e1 = expf(x1 - mx);
    float s = wredu_sum(e0 + e1);
    // gather logit[cls_reg] (all lanes participate: shfl sources must be live)
    float g0 = __shfl(x0, cls_reg, 64);
    float g1 = __shfl(x1, cls_reg, 64);
    float xsel = (cls_reg < 64) ? g0 : g1;
    float negp = -(expf(xsel - mx) / s);  // == -probs[cls_reg], same formula

    float4 pb = pbv[b * NQ + q];
    float ax1 = pb.x - 0.5f * pb.z, ay1 = pb.y - 0.5f * pb.w;
    float ax2 = pb.x + 0.5f * pb.z, ay2 = pb.y + 0.5f * pb.w;
    float areaA = (ax2 - ax1) * (ay2 - ay1);
    if (lane < NM) {
      hc[lane * PITCH + q] =
          pair_cost(ax1, ay1, ax2, ay2, areaA, pb, t_reg, negp);
    }
  }
  __syncthreads();            // all 16 waves alive here
  if (wave != 0) return;      // wave 0 continues barrier-free (single wave)

  // ===== R6 ALGORITHM (v=0, row-argmin greedy, R6 tie-break) with u in =====
  // ===== registers, p/way in LDS, prefetched p[j1], DPP reductions and  =====
  // ===== v_readlane broadcasts on the serial critical path              =====

  // ---- row reduction: lane i scans its row (dual accumulator halves the
  // ---- serial compare chain; merge preserves lowest-index-on-tie) ----
  float u_reg = 0.f;
  int am_reg = 0;
  if (lane < HN) {
    const float* r = &hc[lane * PITCH];
    float mn0 = BIG, mn1 = BIG;
    int a0 = 0, a1 = 1;
    for (int j = 0; j < HM; j += 2) {  // HM=300 even
      float va = r[j], vb = r[j + 1];
      if (va < mn0) { mn0 = va; a0 = j; }
      if (vb < mn1) { mn1 = vb; a1 = j + 1; }
    }
    bool takeOdd = (mn1 < mn0) || (mn1 == mn0 && a1 < a0);
    u_reg = takeOdd ? mn1 : mn0;
    am_reg = takeOdd ? a1 : a0;
  }

  // ---- greedy tight-edge assignment (R6 semantics; register assigned-mask) --
  unsigned amask = 0;   // bit k of lane l: col l+64k assigned
  unsigned long long pending = 0;
  for (int i = 0; i < HN; i++) {
    int jm = rli(am_reg, i);
    unsigned mrem = (unsigned)rli((int)amask, jm & 63);
    if (!((mrem >> (jm >> 6)) & 1u)) {
      if (lane == (jm & 63)) amask |= 1u << (jm >> 6);
      if (lane == 0) p[jm] = i;
    } else {
      pending |= 1ull << i;
    }
  }
  FENCE();

  // ---- JV augmenting searches ----
  float v_r[5], minv_r[5];
#pragma unroll
  for (int k = 0; k < 5; k++) v_r[k] = 0.f;

  while (pending) {
    int i_start = (int)__ffsll((long long)pending) - 1;
    pending &= pending - 1;
#pragma unroll
    for (int k = 0; k < 5; k++) minv_r[k] = BIG;
    unsigned usedc = 0;
    unsigned long long used_rows = 1ull << i_start;
    int i0 = i_start, j0 = HM, jfree = -1;
    float ui0 = rlf(u_reg, i0);

    while (true) {
      float best = BIG; int bj = 0;
      const float* hrow = &hc[i0 * PITCH];
#pragma unroll
      for (int k = 0; k < 5; k++) {
        int j = lane + 64 * k;
        if (j < HM && !((usedc >> k) & 1u)) {
          float cur = hrow[j] - ui0 - v_r[k];
          if (cur < minv_r[k]) { minv_r[k] = cur; way[j] = j0; }
          if (minv_r[k] < best) { best = minv_r[k]; bj = j; }
        }
      }
      // R6-verbatim tie-break: min value, lowest lane among equals
      float wmin = wredu_min(best);
      unsigned long long ball = __ballot(best == wmin);
      int src = (int)__ffsll((long long)ball) - 1;
      int j1 = rli(bj, src);
      float delta = wmin;

      int psel = p[j1];   // LDS read issued early; overlaps dual update below

      // dual updates (used set EXCLUDES j1, matching ref ordering);
      // virtual col: u[i_start] += delta via used_rows bit
      if ((used_rows >> lane) & 1ull) u_reg += delta;
#pragma unroll
      for (int k = 0; k < 5; k++) {
        int j = lane + 64 * k;
        if (j < HM) {
          if ((usedc >> k) & 1u) v_r[k] -= delta;
          else                   minv_r[k] -= delta;
        }
      }
      if (lane == (j1 & 63)) usedc |= 1u << (j1 >> 6);

      if (psel == -1) { jfree = j1; break; }
      i0 = psel;
      used_rows |= 1ull << i0;
      ui0 = rlf(u_reg, i0);  // new row not in used set: value is final
      j0 = j1;
    }

    // augment along `way` (all lanes identical walk; same-value writes)
    int jj = jfree;
    while (jj != HM) {
      int jn = way[jj];
      int pv = (jn == HM) ? i_start : p[jn];
      p[jj] = pv;
      jj = jn;
    }
    FENCE();
  }

  // ---- emit: q[i] = col of row i; rank-sort; write as float32 ----
  for (int j = lane; j < HM; j += 64) {
    int r = p[j];
    if (r >= 0) qarr[r] = j;
  }
  FENCE();
  if (lane < HN) {
    int qi = qarr[lane];
    int rank = 0;
    for (int t = 0; t < HN; t++) rank += (qarr[t] < qi);
    outp[(size_t)b * NM + rank] = (float)qi;         // pred_idx
    outp[BM + (size_t)b * NM + rank] = (float)lane;  // gt_idx
  }
}

extern "C" void kernel_launch(void* const* d_in, const int* in_sizes, int n_in,
                              void* d_out, int out_size, void* d_ws, size_t ws_size,
                              hipStream_t stream) {
  const float* logits = (const float*)d_in[0];   // (32,300,92)
  const float* pboxes = (const float*)d_in[1];   // (32,300,4)
  const int*   tlab   = (const int*)d_in[2];     // (32,50)
  const float* tbox   = (const float*)d_in[3];   // (32,50,4)
  float* out = (float*)d_out;

  fused_kernel<<<dim3(NBLOCKS), dim3(1024), 0, stream>>>(
      logits, pboxes, tlab, tbox, out);
}